// Round 1
// baseline (1151.374 us; speedup 1.0000x reference)
//
#include <hip/hip_runtime.h>
#include <cstdint>

#define ALPHA 0.3f
#define NEG_FILL -200.0f

typedef unsigned short ushort_t;
typedef __attribute__((ext_vector_type(8))) short bf16x8;
typedef __attribute__((ext_vector_type(4))) float f32x4;

constexpr int Bc = 2, Vc = 50000, Tc = 3, Nc = 32;
constexpr int Fc = 128, FEc = 128, Uc = 128, Ec = 300000;
constexpr int TNc = Tc * Nc;     // 96
constexpr int BVc = Bc * Vc;     // 100000
constexpr int TEc = Tc * Ec;     // 900000
constexpr int KTOT = Tc * FEc;   // 384 (vertex GEMM K)
constexpr int CAP = 64;          // per-vertex edge bucket capacity

__device__ __forceinline__ ushort_t f2bf(float f) {       // RNE float->bf16 bits
    unsigned u = __float_as_uint(f);
    return (ushort_t)((u + 0x7fffu + ((u >> 16) & 1u)) >> 16);
}

// ---------------------------------------------------------------------------
// K0: W_dense -> bf16, transposed [u][k], XOR-swizzled in 8-elem granules.
// Layout per t: 2 k-chunks of 1024 granules; granule (u*8+pos) holds
// W[kt*64 + (pos^(u&7))*8 + j][u].  (unchanged from previous version)
// ---------------------------------------------------------------------------
__global__ __launch_bounds__(256) void k_wprep(
    const float* __restrict__ Wd, ushort_t* __restrict__ Wt)
{
    const int g = blockIdx.x * 256 + threadIdx.x;
    if (g >= Tc * 2048) return;
    const int t = g >> 11, rem = g & 2047;
    const int kt = rem >> 10, gi = rem & 1023;
    const int u = gi >> 3, pos = gi & 7;
    const int kq = pos ^ (u & 7);
    const float* Ws = Wd + (size_t)t * FEc * Uc;
    bf16x8 val;
#pragma unroll
    for (int j = 0; j < 8; ++j)
        val[j] = (short)f2bf(Ws[(size_t)(kt * 64 + kq * 8 + j) * Uc + u]);
    *(bf16x8*)&Wt[(size_t)g * 8] = val;
}

// ---------------------------------------------------------------------------
// K1: wv[t][f] = sum_u Wd[t][f][u] * Wa[F+u];  ct[t] = sum_u bd[t][u]*Wa[F+u] + ba
// Tiny (3 blocks). Lets the edge pass compute the attention logit as a
// 128-float dot instead of needing the full edge GEMM.
// ---------------------------------------------------------------------------
__global__ __launch_bounds__(128) void k_wv(
    const float* __restrict__ Wd, const float* __restrict__ bd,
    const float* __restrict__ Wa, const float* __restrict__ ba,
    float* __restrict__ wv, float* __restrict__ ct)
{
    const int t = blockIdx.x, f = threadIdx.x;
    const float* W = Wd + (size_t)t * FEc * Uc + (size_t)f * Uc;
    float acc = 0.f;
    for (int u = 0; u < Uc; ++u) acc += W[u] * Wa[Fc + u];
    wv[t * FEc + f] = acc;
    if (f == 0) {
        float c = ba[0];
        for (int u = 0; u < Uc; ++u) c += bd[t * Uc + u] * Wa[Fc + u];
        ct[t] = c;
    }
}

// ---------------------------------------------------------------------------
// K2: per-vertex feature dot  fdot[bv] = features[bv,:] . W_att[:F]
// ---------------------------------------------------------------------------
__global__ __launch_bounds__(256) void k_fdot(
    const float* __restrict__ feat, const float* __restrict__ Wa,
    float* __restrict__ fdot)
{
    const int wv = blockIdx.x * 4 + (threadIdx.x >> 6);
    const int lane = threadIdx.x & 63;
    if (wv >= BVc) return;
    const float* fr = feat + (size_t)wv * Fc;
    float p = fr[lane] * Wa[lane] + fr[lane + 64] * Wa[lane + 64];
#pragma unroll
    for (int x = 1; x < 64; x <<= 1) p += __shfl_xor(p, x);
    if (lane == 0) fdot[wv] = p;
}

// ---------------------------------------------------------------------------
// K3: one wave per edge. Streams ef (512B/row, fully coalesced), computes
// logit = leaky(ef.wv[t] + fdot[vtx] + ct[t]), fills per-vertex bucket with
// packed (eid | s<<20 | t<<25). No global keyg, no dotx.
// ---------------------------------------------------------------------------
__global__ __launch_bounds__(256) void k_edge(
    const int* __restrict__ eidx, const float* __restrict__ ef,
    const float* __restrict__ wv, const float* __restrict__ ct,
    const float* __restrict__ fdot, float* __restrict__ logits,
    int* __restrict__ cnt, int* __restrict__ elist)
{
    const int w = blockIdx.x * 4 + (threadIdx.x >> 6);   // global edge id
    const int lane = threadIdx.x & 63;
    if (w >= TEc) return;
    const int t = w / Ec;
    const float2 efv = *(const float2*)&ef[(size_t)w * FEc + lane * 2];
    const float2 wvv = *(const float2*)&wv[t * FEc + lane * 2];
    float p = efv.x * wvv.x + efv.y * wvv.y;
#pragma unroll
    for (int x = 1; x < 64; x <<= 1) p += __shfl_xor(p, x);
    const int ev = (lane < 3) ? eidx[(size_t)w * 3 + lane] : 0;
    const int b = __shfl(ev, 0);
    const int v = __shfl(ev, 1);
    const int s = __shfl(ev, 2);
    if (lane == 0) {
        const int vtx = b * Vc + v;
        float z = p + ct[t] + fdot[vtx];
        logits[w] = (z >= 0.f) ? z : ALPHA * z;
        const int pos = atomicAdd(&cnt[vtx], 1);
        if (pos < CAP) elist[(size_t)vtx * CAP + pos] = w | (s << 20) | (t << 25);
    }
}

// ---------------------------------------------------------------------------
// K4: per-vertex: slot winners via LDS atomicMax over the <=64 bucket entries,
// softmax over 96 slots, degree from adjacency, per-type att sums S[t], and
// att-weighted aggregation of raw ef rows into agg[vtx][3][128] (f32).
// ---------------------------------------------------------------------------
__global__ __launch_bounds__(128) void k_vertex(
    const int* __restrict__ adj, const float* __restrict__ logits,
    const int* __restrict__ cnt, const int* __restrict__ elist,
    const float* __restrict__ ef, float* __restrict__ agg,
    float4* __restrict__ s4)
{
    const int vtx = blockIdx.x;
    const int tid = threadIdx.x;
    const int wave = tid >> 6, lane = tid & 63;
    __shared__ int   skey[TNc];
    __shared__ int   epack[CAP];
    __shared__ float att[TNc];
    __shared__ float redf[2];
    __shared__ float reds[2];
    __shared__ int   redi[2];
    __shared__ float sS[3];

    const int ne = min(cnt[vtx], CAP);
    if (tid < TNc) skey[tid] = -1;
    if (tid < 3)   sS[tid] = 0.f;
    __syncthreads();
    if (tid < ne) {
        const int p = elist[(size_t)vtx * CAP + tid];
        epack[tid] = p;
        atomicMax(&skey[((p >> 25) & 3) * Nc + ((p >> 20) & 31)], p & 0xFFFFF);
    }
    __syncthreads();

    float l = -1e30f; int dg = 0;
    if (tid < TNc) {
        const int k = skey[tid];
        l = (k >= 0) ? logits[k] : NEG_FILL;
        dg = (adj[(size_t)vtx * TNc + tid] >= 0) ? 1 : 0;
    }
    float m = l; int d = dg;
#pragma unroll
    for (int x = 1; x < 64; x <<= 1) {
        m = fmaxf(m, __shfl_xor(m, x));
        d += __shfl_xor(d, x);
    }
    if (lane == 0) { redf[wave] = m; redi[wave] = d; }
    __syncthreads();
    m = fmaxf(redf[0], redf[1]);
    const float degree = (float)(redi[0] + redi[1]);
    float e = (tid < TNc) ? expf(l - m) : 0.f;
    float sum = e;
#pragma unroll
    for (int x = 1; x < 64; x <<= 1) sum += __shfl_xor(sum, x);
    if (lane == 0) reds[wave] = sum;
    __syncthreads();
    const float invden = 1.0f / (reds[0] + reds[1]);
    if (tid < TNc) att[tid] = e * invden;
    __syncthreads();

    if (tid < ne) {
        const int p = epack[tid];
        atomicAdd(&sS[(p >> 25) & 3], att[((p >> 25) & 3) * Nc + ((p >> 20) & 31)]);
    }
    float a0 = 0.f, a1 = 0.f, a2 = 0.f;
    for (int it = 0; it < ne; ++it) {
        const int p = epack[it];
        const int eid = p & 0xFFFFF;
        const int t = (p >> 25) & 3;
        const float w = att[t * Nc + ((p >> 20) & 31)];
        const float x = ef[(size_t)eid * FEc + tid];
        if (t == 0) a0 += w * x; else if (t == 1) a1 += w * x; else a2 += w * x;
    }
    __syncthreads();
    const size_t base = (size_t)vtx * KTOT;
    agg[base + tid]           = a0;
    agg[base + FEc + tid]     = a1;
    agg[base + 2 * FEc + tid] = a2;
    if (tid == 0) s4[vtx] = make_float4(sS[0], sS[1], sS[2], degree);
}

// ---------------------------------------------------------------------------
// K5: vertex-level MFMA GEMM: out[v,:] = (sum_t agg[v,t,:].Wd[t] + sum_t S_t*bd[t,:]) * deg
// Tile 128 vertices x 128 u, K = 3*128 in 6 chunks of 64. Same LDS granule
// swizzle + MFMA structure as the previous (verified) edge GEMM.
// ---------------------------------------------------------------------------
__global__ __launch_bounds__(256) void k_out(
    const float* __restrict__ agg, const ushort_t* __restrict__ Wt,
    const float* __restrict__ bd, const float4* __restrict__ s4,
    float* __restrict__ out)
{
    __shared__ ushort_t sA[128 * 64];  // 16 KB
    __shared__ ushort_t sW[128 * 64];  // 16 KB
    const int e0  = blockIdx.x * 128;
    const int tid = threadIdx.x;
    const int wave = tid >> 6, lane = tid & 63;
    const int ln = lane & 15, quad = lane >> 4;
    const int m0 = (wave >> 1) * 64, n0 = (wave & 1) * 64;

    f32x4 acc[4][4];
#pragma unroll
    for (int i = 0; i < 4; ++i)
#pragma unroll
        for (int j = 0; j < 4; ++j)
#pragma unroll
            for (int r = 0; r < 4; ++r) acc[i][j][r] = 0.f;

    for (int c = 0; c < 6; ++c) {                 // c = t*2 + kt
        const int t = c >> 1, kt = c & 1;
        __syncthreads();
#pragma unroll
        for (int it = 0; it < 4; ++it) {
            const int g = tid + it * 256;
            const int row = g >> 3, pos = g & 7;
            const int kq = pos ^ (row & 7);
            bf16x8 val;
            if (e0 + row < BVc) {
                const float* s = agg + (size_t)(e0 + row) * KTOT + t * FEc + kt * 64 + kq * 8;
                float4 f0 = *(const float4*)s;
                float4 f1 = *(const float4*)(s + 4);
                val[0] = (short)f2bf(f0.x); val[1] = (short)f2bf(f0.y);
                val[2] = (short)f2bf(f0.z); val[3] = (short)f2bf(f0.w);
                val[4] = (short)f2bf(f1.x); val[5] = (short)f2bf(f1.y);
                val[6] = (short)f2bf(f1.z); val[7] = (short)f2bf(f1.w);
            } else {
#pragma unroll
                for (int q = 0; q < 8; ++q) val[q] = 0;
            }
            *(bf16x8*)&sA[(size_t)g * 8] = val;
            *(bf16x8*)&sW[(size_t)g * 8] = *(const bf16x8*)&Wt[(size_t)(c * 1024 + g) * 8];
        }
        __syncthreads();
#pragma unroll
        for (int kk = 0; kk < 2; ++kk) {
            bf16x8 af[4], bfr[4];
            const int p = (kk * 4 + quad) ^ (ln & 7);
#pragma unroll
            for (int i = 0; i < 4; ++i) {
                const int row = m0 + i * 16 + ln;
                af[i] = *(const bf16x8*)&sA[(size_t)(row * 8 + p) * 8];
            }
#pragma unroll
            for (int j = 0; j < 4; ++j) {
                const int row = n0 + j * 16 + ln;
                bfr[j] = *(const bf16x8*)&sW[(size_t)(row * 8 + p) * 8];
            }
#pragma unroll
            for (int i = 0; i < 4; ++i)
#pragma unroll
                for (int j = 0; j < 4; ++j)
                    acc[i][j] = __builtin_amdgcn_mfma_f32_16x16x32_bf16(
                        af[i], bfr[j], acc[i][j], 0, 0, 0);
        }
    }

    // epilogue: + S.bd bias, * degree
    float bdv0[4], bdv1[4], bdv2[4];
#pragma unroll
    for (int j = 0; j < 4; ++j) {
        const int u = n0 + j * 16 + ln;
        bdv0[j] = bd[u];
        bdv1[j] = bd[Uc + u];
        bdv2[j] = bd[2 * Uc + u];
    }
#pragma unroll
    for (int i = 0; i < 4; ++i) {
#pragma unroll
        for (int r = 0; r < 4; ++r) {
            const int e = e0 + m0 + i * 16 + quad * 4 + r;
            if (e < BVc) {
                const float4 sv = s4[e];
#pragma unroll
                for (int j = 0; j < 4; ++j) {
                    const float val = (acc[i][j][r] + sv.x * bdv0[j] + sv.y * bdv1[j]
                                       + sv.z * bdv2[j]) * sv.w;
                    out[(size_t)e * Uc + n0 + j * 16 + ln] = val;
                }
            }
        }
    }
}

// ---------------------------------------------------------------------------
extern "C" void kernel_launch(void* const* d_in, const int* in_sizes, int n_in,
                              void* d_out, int out_size, void* d_ws, size_t ws_size,
                              hipStream_t stream)
{
    const int*   adj  = (const int*)  d_in[0];  // (B,V,T,N)
    const float* feat = (const float*)d_in[1];  // (B,V,F)
    const int*   eidx = (const int*)  d_in[2];  // (T,E,3)
    const float* ef   = (const float*)d_in[3];  // (T,E,FE)
    const float* Wd   = (const float*)d_in[4];  // (T,FE,U)
    const float* bd   = (const float*)d_in[5];  // (T,U)
    const float* Wa   = (const float*)d_in[6];  // (F+U,1)
    const float* ba   = (const float*)d_in[7];  // (1,)
    float* out = (float*)d_out;

    char* ws = (char*)d_ws;
    float*    logits = (float*)ws;    ws += (size_t)TEc * 4;             // 3.6 MB
    float*    agg    = (float*)ws;    ws += (size_t)BVc * KTOT * 4;      // 153.6 MB
    float4*   s4     = (float4*)ws;   ws += (size_t)BVc * 16;            // 1.6 MB
    int*      cnt    = (int*)ws;      ws += (size_t)BVc * 4;             // 0.4 MB
    int*      elist  = (int*)ws;      ws += (size_t)BVc * CAP * 4;       // 25.6 MB
    float*    fdot   = (float*)ws;    ws += (size_t)BVc * 4;             // 0.4 MB
    float*    wv     = (float*)ws;    ws += (size_t)Tc * FEc * 4;        // 1.5 KB
    float*    ctb    = (float*)ws;    ws += 16;
    ushort_t* Wt     = (ushort_t*)ws; ws += (size_t)Tc * 16384 * 2;      // 96 KB

    hipMemsetAsync(cnt, 0, (size_t)BVc * 4, stream);

    k_wprep<<<(Tc * 2048 + 255) / 256, 256, 0, stream>>>(Wd, Wt);
    k_wv<<<Tc, 128, 0, stream>>>(Wd, bd, Wa, ba, wv, ctb);
    k_fdot<<<BVc / 4, 256, 0, stream>>>(feat, Wa, fdot);
    k_edge<<<TEc / 4, 256, 0, stream>>>(eidx, ef, wv, ctb, fdot, logits, cnt, elist);
    k_vertex<<<BVc, 128, 0, stream>>>(adj, logits, cnt, elist, ef, agg, s4);
    k_out<<<(BVc + 127) / 128, 256, 0, stream>>>(agg, Wt, bd, s4, out);
}